// Round 1
// baseline (855.177 us; speedup 1.0000x reference)
//
#include <hip/hip_runtime.h>
#include <hip/hip_bf16.h>

#define S 2048
#define D 64
#define TQ 64
#define TK 64
#define LDSS 72  // padded LDS row stride in shorts (144 B, 16B-aligned, breaks bank pattern)

typedef __attribute__((ext_vector_type(8))) short short8;
typedef __attribute__((ext_vector_type(4))) float f32x4;

static __device__ inline unsigned short f2bf(float x) {
  union { float f; unsigned u; } t; t.f = x;
  unsigned r = t.u + 0x7FFF + ((t.u >> 16) & 1);   // round-to-nearest-even
  return (unsigned short)(r >> 16);
}

__global__ __launch_bounds__(256) void attn_kernel(
    const float* __restrict__ q, const float* __restrict__ k,
    const float* __restrict__ v, float* __restrict__ out_res,
    float* __restrict__ out_attn) {
  __shared__ unsigned short sQ[TQ * LDSS];
  __shared__ unsigned short sK[TK * LDSS];
  __shared__ unsigned short sVt[D * LDSS];
  __shared__ unsigned short sP[TQ * LDSS];

  const int tid = threadIdx.x;
  const int wv = tid >> 6;
  const int lane = tid & 63;
  const int quad = lane >> 4;
  const int l16 = lane & 15;

  const int bh = blockIdx.x >> 5;   // 32 q-tiles per (b,h)
  const int qt = blockIdx.x & 31;

  const float* qg = q + ((size_t)bh * S + qt * TQ) * D;
  const float* kg = k + (size_t)bh * S * D;
  const float* vg = v + (size_t)bh * S * D;

  // stage Q tile, pre-scaled by 1/sqrt(D)=0.125, as bf16
  for (int i = 0; i < 4; ++i) {
    int f4 = tid + i * 256;
    float4 val = ((const float4*)qg)[f4];
    int flat = f4 * 4;
    int r = flat >> 6, c = flat & 63;
    ushort4 w4;
    w4.x = f2bf(val.x * 0.125f);
    w4.y = f2bf(val.y * 0.125f);
    w4.z = f2bf(val.z * 0.125f);
    w4.w = f2bf(val.w * 0.125f);
    *(ushort4*)(&sQ[r * LDSS + c]) = w4;
  }

  float m[4], l[4];
  for (int r = 0; r < 4; ++r) { m[r] = -3.0e38f; l[r] = 0.f; }

  const int aoff = (16 * wv + l16) * LDSS;  // A-fragment row base for this wave

  // ---------------- pass 1: softmax stats (m, l) ----------------
  for (int kt = 0; kt < S / TK; ++kt) {
    __syncthreads();
    const float* kgt = kg + kt * TK * D;
    for (int i = 0; i < 4; ++i) {
      int f4 = tid + i * 256;
      float4 val = ((const float4*)kgt)[f4];
      int flat = f4 * 4;
      int r = flat >> 6, c = flat & 63;
      ushort4 w4;
      w4.x = f2bf(val.x); w4.y = f2bf(val.y);
      w4.z = f2bf(val.z); w4.w = f2bf(val.w);
      *(ushort4*)(&sK[r * LDSS + c]) = w4;
    }
    __syncthreads();

    f32x4 acc[4] = {};
    for (int h = 0; h < 2; ++h) {
      short8 a = *(const short8*)(&sQ[aoff + quad * 8 + 32 * h]);
      for (int ct = 0; ct < 4; ++ct) {
        short8 b = *(const short8*)(&sK[(ct * 16 + l16) * LDSS + quad * 8 + 32 * h]);
        acc[ct] = __builtin_amdgcn_mfma_f32_16x16x32_bf16(a, b, acc[ct], 0, 0, 0);
      }
    }
    for (int r = 0; r < 4; ++r) {
      float x = fmaxf(fmaxf(acc[0][r], acc[1][r]), fmaxf(acc[2][r], acc[3][r]));
      for (int off = 1; off < 16; off <<= 1) x = fmaxf(x, __shfl_xor(x, off, 64));
      float mn = fmaxf(m[r], x);
      float e = __expf(acc[0][r] - mn) + __expf(acc[1][r] - mn)
              + __expf(acc[2][r] - mn) + __expf(acc[3][r] - mn);
      for (int off = 1; off < 16; off <<= 1) e += __shfl_xor(e, off, 64);
      l[r] = l[r] * __expf(m[r] - mn) + e;
      m[r] = mn;
    }
  }

  float rl[4];
  for (int r = 0; r < 4; ++r) rl[r] = 1.0f / l[r];

  f32x4 accO[4] = {};
  float* attn_base = out_attn + (size_t)bh * S * S + (size_t)(qt * TQ) * S;

  // ---------------- pass 2: attn write + PV ----------------
  for (int kt = 0; kt < S / TK; ++kt) {
    __syncthreads();   // prior iteration's MFMA reads of sK/sVt done
    const float* kgt = kg + kt * TK * D;
    const float* vgt = vg + kt * TK * D;
    for (int i = 0; i < 4; ++i) {
      int f4 = tid + i * 256;
      float4 val = ((const float4*)kgt)[f4];
      int flat = f4 * 4;
      int r = flat >> 6, c = flat & 63;
      ushort4 w4;
      w4.x = f2bf(val.x); w4.y = f2bf(val.y);
      w4.z = f2bf(val.z); w4.w = f2bf(val.w);
      *(ushort4*)(&sK[r * LDSS + c]) = w4;
      float4 vv = ((const float4*)vgt)[f4];
      sVt[(c + 0) * LDSS + r] = f2bf(vv.x);   // transpose V into LDS
      sVt[(c + 1) * LDSS + r] = f2bf(vv.y);
      sVt[(c + 2) * LDSS + r] = f2bf(vv.z);
      sVt[(c + 3) * LDSS + r] = f2bf(vv.w);
    }
    __syncthreads();

    f32x4 acc[4] = {};
    for (int h = 0; h < 2; ++h) {
      short8 a = *(const short8*)(&sQ[aoff + quad * 8 + 32 * h]);
      for (int ct = 0; ct < 4; ++ct) {
        short8 b = *(const short8*)(&sK[(ct * 16 + l16) * LDSS + quad * 8 + 32 * h]);
        acc[ct] = __builtin_amdgcn_mfma_f32_16x16x32_bf16(a, b, acc[ct], 0, 0, 0);
      }
    }
    // normalized p -> attn (fp32 global) + P tile (bf16 LDS)
    for (int ct = 0; ct < 4; ++ct) {
      for (int r = 0; r < 4; ++r) {
        float p = __expf(acc[ct][r] - m[r]) * rl[r];
        int row = 16 * wv + quad * 4 + r;
        attn_base[(size_t)row * S + kt * TK + ct * 16 + l16] = p;
        sP[row * LDSS + ct * 16 + l16] = f2bf(p);
      }
    }
    __syncthreads();   // P visible (also orders vs next overwrite)

    for (int h = 0; h < 2; ++h) {
      short8 a = *(const short8*)(&sP[aoff + quad * 8 + 32 * h]);
      for (int dt = 0; dt < 4; ++dt) {
        short8 b = *(const short8*)(&sVt[(dt * 16 + l16) * LDSS + quad * 8 + 32 * h]);
        accO[dt] = __builtin_amdgcn_mfma_f32_16x16x32_bf16(a, b, accO[dt], 0, 0, 0);
      }
    }
  }

  float* res_base = out_res + ((size_t)bh * S + qt * TQ) * D;
  for (int dt = 0; dt < 4; ++dt) {
    for (int r = 0; r < 4; ++r) {
      int row = 16 * wv + quad * 4 + r;
      res_base[row * D + dt * 16 + l16] = accO[dt][r];
    }
  }
}

extern "C" void kernel_launch(void* const* d_in, const int* in_sizes, int n_in,
                              void* d_out, int out_size, void* d_ws, size_t ws_size,
                              hipStream_t stream) {
  const float* q = (const float*)d_in[0];
  const float* k = (const float*)d_in[1];
  const float* v = (const float*)d_in[2];
  float* out_res = (float*)d_out;
  float* out_attn = out_res + (size_t)2 * 16 * 2048 * 64;  // result first, then attn

  const int B = 2, H = 16;
  dim3 grid(B * H * (S / TQ));  // 1024 blocks
  dim3 block(256);
  attn_kernel<<<grid, block, 0, stream>>>(q, k, v, out_res, out_attn);
}